// Round 13
// baseline (342.959 us; speedup 1.0000x reference)
//
#include <hip/hip_runtime.h>
#include <hip/hip_bf16.h>

#define EE 160000
#define NNODES 10000

using bf16 = __hip_bfloat16;
using bf16x8 = __attribute__((ext_vector_type(8))) short;
using short4v = __attribute__((ext_vector_type(4))) short;
using f32x4  = __attribute__((ext_vector_type(4))) float;

__device__ __forceinline__ float silu_f(float x) { return x / (1.0f + __expf(-x)); }
__device__ __forceinline__ float b2f(bf16 v) { return __bfloat162float(v); }
__device__ __forceinline__ bf16 f2b(float v) { return __float2bfloat16(v); }

__device__ __forceinline__ unsigned bfbits(float v) {
    union { float f; unsigned u; } a; a.f = v;
    return (a.u + 0x7fffu + ((a.u >> 16) & 1u)) >> 16;
}
__device__ __forceinline__ unsigned pack2(float a, float b) {
    return bfbits(a) | (bfbits(b) << 16);
}
__device__ __forceinline__ void unpack2(unsigned u, float& a, float& b) {
    union { unsigned x; float f; } lo, hi;
    lo.x = u << 16; hi.x = u & 0xffff0000u;
    a = lo.f; b = hi.f;
}
__device__ __forceinline__ float bs2f(short s) {
    union { unsigned u; float f; } x; x.u = ((unsigned)(unsigned short)s) << 16;
    return x.f;
}

// 1/(16*sqrt(8)), 0.5/sqrt(8), 1/sqrt(8)
#define INV_AVGN_SQM 0.02209708691207961f
#define HALF_INV_SQM 0.17677669529663687f
#define INV_SQM      0.35355339059327373f

// ---------------------------------------------------------------------------
// CSR build
// ---------------------------------------------------------------------------
__global__ void kCnt(const int* __restrict__ eidx, int* __restrict__ deg)
{
    const int e = blockIdx.x * 256 + threadIdx.x;
    atomicAdd(&deg[eidx[e]], 1);
}

__global__ void kScan(const int* __restrict__ deg, int* __restrict__ off)
{
    __shared__ int part[256];
    const int t = threadIdx.x;
    int loc[40];
    int s = 0;
#pragma unroll
    for (int i = 0; i < 40; i++) {
        const int idx = t * 40 + i;
        const int v = (idx < NNODES) ? deg[idx] : 0;
        loc[i] = s;
        s += v;
    }
    part[t] = s;
    __syncthreads();
    for (int d = 1; d < 256; d <<= 1) {
        const int v = (t >= d) ? part[t - d] : 0;
        __syncthreads();
        part[t] += v;
        __syncthreads();
    }
    const int base = (t == 0) ? 0 : part[t - 1];
#pragma unroll
    for (int i = 0; i < 40; i++) {
        const int idx = t * 40 + i;
        if (idx < NNODES) off[idx] = base + loc[i];
    }
    if (t == 255) off[NNODES] = part[255];
}

__global__ void kFill(const int* __restrict__ eidx, int* __restrict__ cur,
                      const int* __restrict__ off, int* __restrict__ elist)
{
    const int e = blockIdx.x * 256 + threadIdx.x;
    const int c = eidx[e];
    const int pos = atomicAdd(&cur[c], 1);
    elist[off[c] + pos] = e;
}

// ---------------------------------------------------------------------------
// kPrepA: w1/w2/wm0 -> wAtF fragment-major bf16 [kc=k/8][304 cols][8]
// ---------------------------------------------------------------------------
__global__ void kPrepA(const float* __restrict__ w1, const float* __restrict__ w2,
                       const float* __restrict__ wm0, short* __restrict__ wAtF)
{
    const int t = blockIdx.x * 256 + threadIdx.x;
    if (t >= 38912) return;
    const int k = t & 127, c = t >> 7;
    float v;
    if (c < 128)      v = w1[k * 128 + c];
    else if (c < 256) v = w2[k * 128 + (c - 128)];
    else              v = wm0[k * 48 + (c - 256)];
    wAtF[((k >> 3) * 304 + c) * 8 + (k & 7)] = (short)bfbits(v);
}

// ---------------------------------------------------------------------------
// kPrepB: -> BtF fragment-major bf16 [kc][672][8]
//  cols 0..383: layer-0 per-irrep ; 384..511: latw ; 512..575: l2fo1(+64)
//  576..639: l2fn1(+64) ; 640..647: finw ; 648..671: wm1 (K=128)
// ---------------------------------------------------------------------------
__global__ void kPrepB(const float* __restrict__ l2fo, const float* __restrict__ l2fn,
                       const float* __restrict__ latw, const float* __restrict__ l2fo1,
                       const float* __restrict__ l2fn1, const float* __restrict__ finw,
                       const float* __restrict__ wm1, short* __restrict__ BtF)
{
    const int k = blockIdx.y;
    const int col = blockIdx.x * 256 + threadIdx.x;
    if (col >= 672) return;
    float v = 0.f;
    if (col < 648) {
        if (k < 152) {
            if (col < 384) {
                const int ir = col >> 7, half = (col >> 6) & 1, q = col & 63;
                const float* src = half ? l2fn : l2fo;
                v = src[k * 192 + ir * 64 + q];
            } else if (col < 512)  v = latw[k * 128 + (col - 384)];
            else if (col < 576)    v = l2fo1[k * 192 + 64 + (col - 512)];
            else if (col < 640)    v = l2fn1[k * 192 + 64 + (col - 576)];
            else                   v = finw[k * 8 + (col - 640)];
        }
    } else {
        if (k < 128) v = wm1[k * 24 + (col - 648)];
    }
    BtF[((k >> 3) * 672 + col) * 8 + (k & 7)] = (short)bfbits(v);
}

// ---------------------------------------------------------------------------
// kEnvG: gather env + fused env-linear (per node,d)
// ---------------------------------------------------------------------------
__global__ void kEnvG(const float* __restrict__ wcur, const float* __restrict__ ea,
                      const int* __restrict__ off, const int* __restrict__ elist,
                      const float* __restrict__ wl, float* __restrict__ envc)
{
    const int t = blockIdx.x * 256 + threadIdx.x;
    if (t >= NNODES * 9) return;
    const int n = t / 9;
    const int d = t - n * 9;
    const int irr = (d == 0) ? 0 : ((d < 4) ? 1 : 2);
    float v[8];
#pragma unroll
    for (int q = 0; q < 8; q++) v[q] = 0.0f;
    const int b = off[n], en = off[n + 1];
    for (int j = b; j < en; j++) {
        const int e = elist[j];
        const float ad = ea[e * 9 + d];
        const float* wr = wcur + (size_t)e * 24 + irr;
#pragma unroll
        for (int q = 0; q < 8; q++) v[q] = fmaf(wr[q * 3], ad, v[q]);
    }
#pragma unroll
    for (int u = 0; u < 8; u++) {
        float s = 0.0f;
#pragma unroll
        for (int q = 0; q < 8; q++) s = fmaf(wl[irr * 64 + u * 8 + q], v[q], s);
        envc[n * 72 + u * 9 + d] = s * INV_AVGN_SQM;
    }
}

// ---------------------------------------------------------------------------
// kA0: inputs gather + cutoff + stage0 (16->128) -> h08; eaT; pad chunk
// ---------------------------------------------------------------------------
__global__ __launch_bounds__(256) void kA0(
    const float* __restrict__ ea, const float* __restrict__ eemb,
    const float* __restrict__ nat, const float* __restrict__ elen,
    const float* __restrict__ w0, const int* __restrict__ eidx,
    short* __restrict__ h08, short* __restrict__ latf8s,
    bf16* __restrict__ eaT, float* __restrict__ cutb)
{
    __shared__ float w0s[16 * 128];
    const int t = threadIdx.x;
    const int e = blockIdx.x * 256 + t;
#pragma unroll
    for (int p = 0; p < 8; p++) { const int idx = p * 256 + t; w0s[idx] = w0[idx]; }
    __syncthreads();

    const int ctr = eidx[e];
    const int ngb = eidx[EE + e];
    float tin[16];
#pragma unroll
    for (int k = 0; k < 4; k++) tin[k] = nat[ctr * 4 + k];
#pragma unroll
    for (int k = 0; k < 4; k++) tin[4 + k] = nat[ngb * 4 + k];
#pragma unroll
    for (int k = 0; k < 8; k++) tin[8 + k] = eemb[e * 8 + k];

    const float x = elen[e];
    const float x2 = x * x, x4 = x2 * x2, x6 = x4 * x2, x7 = x6 * x, x8 = x7 * x;
    float cutv = 1.0f - 28.0f * x6 + 48.0f * x7 - 21.0f * x8;
    cutv = (x < 1.0f) ? cutv : 0.0f;
    cutb[e] = cutv;

    const size_t tb = (size_t)(e >> 5);
    const int el = e & 31;
#pragma unroll
    for (int jc = 0; jc < 4; jc++) {
        float a[32];
#pragma unroll
        for (int j = 0; j < 32; j++) a[j] = 0.0f;
#pragma unroll
        for (int k = 0; k < 16; k++) {
            const float v = tin[k];
#pragma unroll
            for (int j = 0; j < 32; j++) a[j] = fmaf(v, w0s[k * 128 + jc * 32 + j], a[j]);
        }
#pragma unroll
        for (int cc = 0; cc < 4; cc++) {
            bf16x8 hv;
#pragma unroll
            for (int jj = 0; jj < 8; jj++) hv[jj] = (short)bfbits(silu_f(a[cc * 8 + jj]));
            *(bf16x8*)(h08 + tb * 4096 + (jc * 4 + cc) * 256 + el * 8) = hv;
        }
    }
    bf16x8 z;
#pragma unroll
    for (int jj = 0; jj < 8; jj++) z[jj] = 0;
    *(bf16x8*)(latf8s + tb * 5120 + 19 * 256 + el * 8) = z;

#pragma unroll
    for (int d = 0; d < 9; d++) eaT[(size_t)d * EE + e] = f2b(ea[e * 9 + d]);
}

// ---------------------------------------------------------------------------
// kAm: MFMA chain. B direct from global wAtF; LDS = A2/A3 (32KB) -> 4 blk/CU.
// ---------------------------------------------------------------------------
__global__ __launch_bounds__(256, 4) void kAm(
    const short* __restrict__ h08, const short* __restrict__ wAtF,
    const float* __restrict__ cutb, short* __restrict__ latf8s,
    float* __restrict__ winiF, float* __restrict__ wcur0)
{
    __shared__ alignas(16) char a2raw[16384];                // A2 / Cs (16 KB)
    __shared__ short A3[8192];                               // 16 KB
    short* A2 = (short*)a2raw;
    float* Cs = (float*)a2raw;

    const int t = threadIdx.x;
    const int eb = blockIdx.x * 64;
    const int lane = t & 63, wid = t >> 6;
    const int wm = wid >> 1, wn = wid & 1;
    const int l15 = lane & 15, kq = lane >> 4;
    const f32x4 zz = {0.f, 0.f, 0.f, 0.f};

    float cutR[2][4];
#pragma unroll
    for (int mi = 0; mi < 2; mi++)
#pragma unroll
        for (int r = 0; r < 4; r++)
            cutR[mi][r] = cutb[eb + wm * 32 + mi * 16 + kq * 4 + r];

    // GEMM1: h1 = silu(h0 @ w1) -> A2   (B cols 0..127)
    {
        f32x4 acc[8];
#pragma unroll
        for (int q = 0; q < 8; q++) acc[q] = zz;
        const size_t ab = (size_t)((eb >> 5) + wm) * 4096 + l15 * 8;
#pragma unroll
        for (int ks = 0; ks < 4; ks++) {
            const int kc = ks * 4 + kq;
            const bf16x8 a0 = *(const bf16x8*)(h08 + ab + kc * 256);
            const bf16x8 a1 = *(const bf16x8*)(h08 + ab + kc * 256 + 128);
            const short* bp = wAtF + (kc * 304 + wn * 64 + l15) * 8;
#pragma unroll
            for (int ni = 0; ni < 4; ni++) {
                const bf16x8 b = *(const bf16x8*)(bp + ni * 16 * 8);
                acc[ni]     = __builtin_amdgcn_mfma_f32_16x16x32_bf16(a0, b, acc[ni], 0, 0, 0);
                acc[4 + ni] = __builtin_amdgcn_mfma_f32_16x16x32_bf16(a1, b, acc[4 + ni], 0, 0, 0);
            }
        }
#pragma unroll
        for (int mi = 0; mi < 2; mi++)
#pragma unroll
            for (int ni = 0; ni < 4; ni++) {
                const int kcol = wn * 64 + ni * 16 + l15;
                const int eb2 = wm * 32 + mi * 16 + (kq << 2);
#pragma unroll
                for (int r = 0; r < 4; r++)
                    A2[(kcol >> 3) * 512 + (eb2 + r) * 8 + (kcol & 7)] =
                        (short)bfbits(silu_f(acc[mi * 4 + ni][r]));
            }
    }
    __syncthreads();

    // GEMM2: latents = (h1 @ w2) * cut -> A3   (B cols 128..255)
    {
        f32x4 acc[8];
#pragma unroll
        for (int q = 0; q < 8; q++) acc[q] = zz;
#pragma unroll
        for (int ks = 0; ks < 4; ks++) {
            const int kc = ks * 4 + kq;
            const bf16x8 a0 = *(const bf16x8*)(A2 + kc * 512 + (wm * 32 + l15) * 8);
            const bf16x8 a1 = *(const bf16x8*)(A2 + kc * 512 + (wm * 32 + 16 + l15) * 8);
            const short* bp = wAtF + (kc * 304 + 128 + wn * 64 + l15) * 8;
#pragma unroll
            for (int ni = 0; ni < 4; ni++) {
                const bf16x8 b = *(const bf16x8*)(bp + ni * 16 * 8);
                acc[ni]     = __builtin_amdgcn_mfma_f32_16x16x32_bf16(a0, b, acc[ni], 0, 0, 0);
                acc[4 + ni] = __builtin_amdgcn_mfma_f32_16x16x32_bf16(a1, b, acc[4 + ni], 0, 0, 0);
            }
        }
#pragma unroll
        for (int mi = 0; mi < 2; mi++)
#pragma unroll
            for (int ni = 0; ni < 4; ni++) {
                const int kcol = wn * 64 + ni * 16 + l15;
                const int eb2 = wm * 32 + mi * 16 + (kq << 2);
#pragma unroll
                for (int r = 0; r < 4; r++)
                    A3[(kcol >> 3) * 512 + (eb2 + r) * 8 + (kcol & 7)] =
                        (short)bfbits(acc[mi * 4 + ni][r] * cutR[mi][r]);
            }
    }
    __syncthreads();
    // copy A3 -> latf8 (coalesced)
#pragma unroll
    for (int p = 0; p < 4; p++) {
        const int i = p * 256 + t;
        const int e = i & 63, kc = i >> 6;
        const bf16x8 v = *(const bf16x8*)(A3 + kc * 512 + e * 8);
        const int eg = eb + e;
        *(bf16x8*)(latf8s + (size_t)(eg >> 5) * 5120 + kc * 256 + (eg & 31) * 8) = v;
    }

    // GEMM3: ewv = latents @ wm0 (wn==0) -> Cs [48][65]   (B cols 256..303)
    if (wn == 0) {
        f32x4 acc[6];
#pragma unroll
        for (int q = 0; q < 6; q++) acc[q] = zz;
#pragma unroll
        for (int ks = 0; ks < 4; ks++) {
            const int kc = ks * 4 + kq;
            const bf16x8 a0 = *(const bf16x8*)(A3 + kc * 512 + (wm * 32 + l15) * 8);
            const bf16x8 a1 = *(const bf16x8*)(A3 + kc * 512 + (wm * 32 + 16 + l15) * 8);
            const short* bp = wAtF + (kc * 304 + 256 + l15) * 8;
#pragma unroll
            for (int ni = 0; ni < 3; ni++) {
                const bf16x8 b = *(const bf16x8*)(bp + ni * 16 * 8);
                acc[ni]     = __builtin_amdgcn_mfma_f32_16x16x32_bf16(a0, b, acc[ni], 0, 0, 0);
                acc[3 + ni] = __builtin_amdgcn_mfma_f32_16x16x32_bf16(a1, b, acc[3 + ni], 0, 0, 0);
            }
        }
#pragma unroll
        for (int mi = 0; mi < 2; mi++)
#pragma unroll
            for (int ni = 0; ni < 3; ni++) {
                const int c = ni * 16 + l15;
                const int eb2 = wm * 32 + mi * 16 + (kq << 2);
#pragma unroll
                for (int r = 0; r < 4; r++)
                    Cs[c * 65 + eb2 + r] = acc[mi * 3 + ni][r];
            }
    }
    __syncthreads();
    for (int i = t; i < 1536; i += 256) {
        const int c = i >> 6, e = i & 63;
        winiF[(size_t)c * EE + eb + e] = Cs[c * 65 + e];
    }
    for (int i = t; i < 1536; i += 256) {
        const int e2 = i / 24, c2 = i - e2 * 24;
        wcur0[(size_t)(eb + e2) * 24 + c2] = Cs[(24 + c2) * 65 + e2];
    }
}

// ---------------------------------------------------------------------------
// kC1: layer-0 interact + invariants
// ---------------------------------------------------------------------------
__global__ __launch_bounds__(256, 1) void kC1(
    const float* __restrict__ winiF, const bf16* __restrict__ eaT,
    const float* __restrict__ envc, const int* __restrict__ eidx,
    unsigned* __restrict__ newfT, short* __restrict__ latf8s)
{
    const int e = blockIdx.x * 256 + threadIdx.x;
    const int ctr = eidx[e];
    float eav[9];
#pragma unroll
    for (int d = 0; d < 9; d++) eav[d] = b2f(eaT[(size_t)d * EE + e]);
    const float* ec = envc + ctr * 72;
    float inv[24];
#pragma unroll
    for (int uh = 0; uh < 4; uh++) {
        const int u0 = 2 * uh;
        float wi0[3], wi1[3];
#pragma unroll
        for (int i = 0; i < 3; i++) {
            wi0[i] = winiF[(size_t)(u0 * 3 + i) * EE + e];
            wi1[i] = winiF[(size_t)((u0 + 1) * 3 + i) * EE + e];
        }
        float nf0[9], nf1[9];
        const float ec00 = ec[u0 * 9 + 0];
        const float ec10 = ec[(u0 + 1) * 9 + 0];
        const float f00 = wi0[0] * eav[0];
        const float f10 = wi1[0] * eav[0];
#pragma unroll
        for (int d = 0; d < 9; d++) {
            const int irr = (d == 0) ? 0 : ((d < 4) ? 1 : 2);
            const float fa = wi0[irr] * eav[d];
            const float fb = wi1[irr] * eav[d];
            nf0[d] = fa * ec00 + ec[u0 * 9 + d] * f00;
            nf1[d] = fb * ec10 + ec[(u0 + 1) * 9 + d] * f10;
        }
#pragma unroll
        for (int d = 0; d < 9; d++) newfT[(size_t)(d * 4 + uh) * EE + e] = pack2(nf0[d], nf1[d]);
        inv[uh * 6 + 0] = sqrtf(nf0[0] * nf0[0] + 1e-8f);
        inv[uh * 6 + 1] = sqrtf(nf0[1]*nf0[1] + nf0[2]*nf0[2] + nf0[3]*nf0[3] + 1e-8f);
        inv[uh * 6 + 2] = sqrtf(nf0[4]*nf0[4] + nf0[5]*nf0[5] + nf0[6]*nf0[6] + nf0[7]*nf0[7] + nf0[8]*nf0[8] + 1e-8f);
        inv[uh * 6 + 3] = sqrtf(nf1[0] * nf1[0] + 1e-8f);
        inv[uh * 6 + 4] = sqrtf(nf1[1]*nf1[1] + nf1[2]*nf1[2] + nf1[3]*nf1[3] + 1e-8f);
        inv[uh * 6 + 5] = sqrtf(nf1[4]*nf1[4] + nf1[5]*nf1[5] + nf1[6]*nf1[6] + nf1[7]*nf1[7] + nf1[8]*nf1[8] + 1e-8f);
    }
    const size_t tb = (size_t)(e >> 5);
    const int el = e & 31;
#pragma unroll
    for (int j = 0; j < 3; j++) {
        bf16x8 iv;
#pragma unroll
        for (int jj = 0; jj < 8; jj++) iv[jj] = (short)bfbits(inv[j * 8 + jj]);
        *(bf16x8*)(latf8s + tb * 5120 + (16 + j) * 256 + el * 8) = iv;
    }
}

// ---------------------------------------------------------------------------
// kFX: merged layer-0 pe_linear (3 irreps) + latw resnet + env-MLP1 mini-GEMM.
// A-fragments register-cached once, reused across 4 GEMM chunks.
// All A8 reads/writes are block-local (own 64-edge tile) -> merge is race-free.
// ---------------------------------------------------------------------------
__global__ __launch_bounds__(256, 4) void kFX(
    short* __restrict__ A8, const short* __restrict__ BtF,
    const float* __restrict__ winiF, const bf16* __restrict__ eaT,
    const unsigned* __restrict__ newfT, const float* __restrict__ cutb,
    unsigned* __restrict__ feat1T, float* __restrict__ wcur1)
{
    __shared__ float Cs[128 * 67];
    float* Cw = Cs;
    const int t = threadIdx.x;
    const int eb = blockIdx.x * 64;
    const int lane = t & 63, wid = t >> 6;
    const int wm = wid >> 1, wn = wid & 1;
    const int l15 = lane & 15, kq = lane >> 4;
    const f32x4 zz = {0.f, 0.f, 0.f, 0.f};
    const size_t ab = (size_t)((eb >> 5) + wm) * 5120 + l15 * 8;
    const int te = t & 63, uh = t >> 6;
    const int eg = eb + te;

    // cache A fragments once (40 VGPRs)
    bf16x8 aF0[5], aF1[5];
#pragma unroll
    for (int ks = 0; ks < 5; ks++) {
        const int kc = ks * 4 + kq;
        aF0[ks] = *(const bf16x8*)(A8 + ab + kc * 256);
        aF1[ks] = *(const bf16x8*)(A8 + ab + kc * 256 + 128);
    }

    for (int c = 0; c < 4; c++) {               // 0..2: irreps ; 3: latw
        f32x4 acc[8];
#pragma unroll
        for (int q = 0; q < 8; q++) acc[q] = zz;
#pragma unroll
        for (int ks = 0; ks < 5; ks++) {
            const int kc = ks * 4 + kq;
            const short* bp = BtF + (kc * 672 + c * 128 + wn * 64 + l15) * 8;
#pragma unroll
            for (int ni = 0; ni < 4; ni++) {
                const bf16x8 b = *(const bf16x8*)(bp + ni * 16 * 8);
                acc[ni]     = __builtin_amdgcn_mfma_f32_16x16x32_bf16(aF0[ks], b, acc[ni], 0, 0, 0);
                acc[4 + ni] = __builtin_amdgcn_mfma_f32_16x16x32_bf16(aF1[ks], b, acc[4 + ni], 0, 0, 0);
            }
        }
        __syncthreads();   // previous chunk's epilogue finished reading Cs
#pragma unroll
        for (int mi = 0; mi < 2; mi++)
#pragma unroll
            for (int ni = 0; ni < 4; ni++) {
                const int cl = wn * 64 + ni * 16 + l15;
                const int el = wm * 32 + mi * 16 + (kq << 2);
                const f32x4 v = acc[mi * 4 + ni];
#pragma unroll
                for (int r = 0; r < 4; r++) Cs[cl * 67 + el + r] = v[r];
            }
        __syncthreads();
        if (c < 3) {
            // layer-0 pe_linear epilogue for irrep c
            const int ir = c;
            const int d0 = (ir == 0) ? 0 : ((ir == 1) ? 1 : 4);
            const int nd = (ir == 0) ? 1 : ((ir == 1) ? 3 : 5);
            float wv[8];
#pragma unroll
            for (int v8 = 0; v8 < 8; v8++) wv[v8] = winiF[(size_t)(v8 * 3 + ir) * EE + eg];
            for (int dd = 0; dd < nd; dd++) {
                const int d = d0 + dd;
                const float ead = b2f(eaT[(size_t)d * EE + eg]);
                float nfv[8];
#pragma unroll
                for (int q = 0; q < 4; q++)
                    unpack2(newfT[(size_t)(d * 4 + q) * EE + eg], nfv[2 * q], nfv[2 * q + 1]);
                float s0 = 0.f, s1 = 0.f;
#pragma unroll
                for (int v8 = 0; v8 < 8; v8++) {
                    const float fe = wv[v8] * ead;
                    s0 += Cs[(uh * 16 + v8) * 67 + te] * fe + Cs[(64 + uh * 16 + v8) * 67 + te] * nfv[v8];
                    s1 += Cs[(uh * 16 + 8 + v8) * 67 + te] * fe + Cs[(64 + uh * 16 + 8 + v8) * 67 + te] * nfv[v8];
                }
                feat1T[(size_t)(d * 4 + uh) * EE + eg] = pack2(s0 * HALF_INV_SQM, s1 * HALF_INV_SQM);
            }
        } else {
            // latent resnet epilogue: l1 = 0.5*old + 0.5*silu(lat_new)*cut -> A8
            const size_t tbq = (size_t)(eg >> 5);
            const int el2 = eg & 31;
            const float cutv = cutb[eg];
#pragma unroll
            for (int cc2 = 0; cc2 < 4; cc2++) {
                const int kc = uh * 4 + cc2;
                short* ap = A8 + tbq * 5120 + kc * 256 + el2 * 8;
                const bf16x8 ov = *(const bf16x8*)ap;
                bf16x8 nv;
#pragma unroll
                for (int jj = 0; jj < 8; jj++) {
                    const float g = Cs[(kc * 8 + jj) * 67 + te];
                    const float o = bs2f(ov[jj]);
                    nv[jj] = (short)bfbits(0.5f * o + 0.5f * silu_f(g) * cutv);
                }
                *(bf16x8*)ap = nv;
            }
        }
    }
    __syncthreads();   // A8 l1 writes visible block-wide; Cs reads done
    // mini-GEMM: wcur1 = l1 @ wm1 (wn==0 waves; B cols 648..671, c<24 valid)
    if (wn == 0) {
        f32x4 acc4[4] = {zz, zz, zz, zz};
#pragma unroll
        for (int ks = 0; ks < 4; ks++) {
            const int kc = ks * 4 + kq;
            const bf16x8 a0 = *(const bf16x8*)(A8 + ab + kc * 256);
            const bf16x8 a1 = *(const bf16x8*)(A8 + ab + kc * 256 + 128);
#pragma unroll
            for (int ni = 0; ni < 2; ni++) {
                const int cc = ni * 16 + l15;
                bf16x8 b;
                if (cc < 24) b = *(const bf16x8*)(BtF + (kc * 672 + 648 + cc) * 8);
                else {
#pragma unroll
                    for (int jj = 0; jj < 8; jj++) b[jj] = 0;
                }
                acc4[ni]     = __builtin_amdgcn_mfma_f32_16x16x32_bf16(a0, b, acc4[ni], 0, 0, 0);
                acc4[2 + ni] = __builtin_amdgcn_mfma_f32_16x16x32_bf16(a1, b, acc4[2 + ni], 0, 0, 0);
            }
        }
#pragma unroll
        for (int mi = 0; mi < 2; mi++)
#pragma unroll
            for (int ni = 0; ni < 2; ni++) {
                const int cc = ni * 16 + l15;
                if (cc < 24) {
                    const int el = wm * 32 + mi * 16 + (kq << 2);
#pragma unroll
                    for (int r = 0; r < 4; r++) Cw[cc * 65 + el + r] = acc4[mi * 2 + ni][r];
                }
            }
    }
    __syncthreads();
    for (int i = t; i < 1536; i += 256) {
        const int e2 = i / 24, c2 = i - e2 * 24;
        wcur1[(size_t)(eb + e2) * 24 + c2] = Cw[c2 * 65 + e2];
    }
}

// ---------------------------------------------------------------------------
// kE1: layer-1 interact + invariants
// ---------------------------------------------------------------------------
__global__ __launch_bounds__(256, 1) void kE1(
    const unsigned* __restrict__ feat1T, const float* __restrict__ envc,
    const int* __restrict__ eidx, unsigned* __restrict__ newfT,
    short* __restrict__ latf8s)
{
    const int e = blockIdx.x * 256 + threadIdx.x;
    const int ctr = eidx[e];
    const float* ec = envc + ctr * 72;
    float inv[24];
#pragma unroll
    for (int uh = 0; uh < 4; uh++) {
        const int u0 = 2 * uh;
        float f0[9], f1[9];
#pragma unroll
        for (int d = 0; d < 9; d++) unpack2(feat1T[(size_t)(d * 4 + uh) * EE + e], f0[d], f1[d]);
        const float ec00 = ec[u0 * 9 + 0];
        const float ec10 = ec[(u0 + 1) * 9 + 0];
        float nf0[9], nf1[9];
#pragma unroll
        for (int d = 0; d < 9; d++) {
            nf0[d] = f0[d] * ec00 + ec[u0 * 9 + d] * f0[0];
            nf1[d] = f1[d] * ec10 + ec[(u0 + 1) * 9 + d] * f1[0];
        }
#pragma unroll
        for (int d = 0; d < 9; d++) newfT[(size_t)(d * 4 + uh) * EE + e] = pack2(nf0[d], nf1[d]);
        inv[uh * 6 + 0] = sqrtf(nf0[0] * nf0[0] + 1e-8f);
        inv[uh * 6 + 1] = sqrtf(nf0[1]*nf0[1] + nf0[2]*nf0[2] + nf0[3]*nf0[3] + 1e-8f);
        inv[uh * 6 + 2] = sqrtf(nf0[4]*nf0[4] + nf0[5]*nf0[5] + nf0[6]*nf0[6] + nf0[7]*nf0[7] + nf0[8]*nf0[8] + 1e-8f);
        inv[uh * 6 + 3] = sqrtf(nf1[0] * nf1[0] + 1e-8f);
        inv[uh * 6 + 4] = sqrtf(nf1[1]*nf1[1] + nf1[2]*nf1[2] + nf1[3]*nf1[3] + 1e-8f);
        inv[uh * 6 + 5] = sqrtf(nf1[4]*nf1[4] + nf1[5]*nf1[5] + nf1[6]*nf1[6] + nf1[7]*nf1[7] + nf1[8]*nf1[8] + 1e-8f);
    }
    const size_t tb = (size_t)(e >> 5);
    const int el = e & 31;
#pragma unroll
    for (int j = 0; j < 3; j++) {
        bf16x8 iv;
#pragma unroll
        for (int jj = 0; jj < 8; jj++) iv[jj] = (short)bfbits(inv[j * 8 + jj]);
        *(bf16x8*)(latf8s + tb * 5120 + (16 + j) * 256 + el * 8) = iv;
    }
}

// ---------------------------------------------------------------------------
// kF2: fused final GEMM (accO1|accN1 + finw) + epilogue -> d_out.
// A-fragments register-cached across both GEMMs. 4 blk/CU.
// ---------------------------------------------------------------------------
__global__ __launch_bounds__(256, 4) void kF2(
    const short* __restrict__ A8, const short* __restrict__ BtF,
    const unsigned* __restrict__ feat1T, const unsigned* __restrict__ newfT,
    float* __restrict__ outp)
{
    __shared__ float Cs[128 * 67];
    __shared__ float Cwf[16 * 67];
    const int t = threadIdx.x;
    const int eb = blockIdx.x * 64;
    const int lane = t & 63, wid = t >> 6;
    const int wm = wid >> 1, wn = wid & 1;
    const int l15 = lane & 15, kq = lane >> 4;
    const f32x4 zz = {0.f, 0.f, 0.f, 0.f};
    const size_t ab = (size_t)((eb >> 5) + wm) * 5120 + l15 * 8;

    bf16x8 aF0[5], aF1[5];
#pragma unroll
    for (int ks = 0; ks < 5; ks++) {
        const int kc = ks * 4 + kq;
        aF0[ks] = *(const bf16x8*)(A8 + ab + kc * 256);
        aF1[ks] = *(const bf16x8*)(A8 + ab + kc * 256 + 128);
    }

    {
        f32x4 acc[8];
#pragma unroll
        for (int q = 0; q < 8; q++) acc[q] = zz;
#pragma unroll
        for (int ks = 0; ks < 5; ks++) {
            const int kc = ks * 4 + kq;
            const short* bp = BtF + (kc * 672 + 512 + wn * 64 + l15) * 8;
#pragma unroll
            for (int ni = 0; ni < 4; ni++) {
                const bf16x8 b = *(const bf16x8*)(bp + ni * 16 * 8);
                acc[ni]     = __builtin_amdgcn_mfma_f32_16x16x32_bf16(aF0[ks], b, acc[ni], 0, 0, 0);
                acc[4 + ni] = __builtin_amdgcn_mfma_f32_16x16x32_bf16(aF1[ks], b, acc[4 + ni], 0, 0, 0);
            }
        }
#pragma unroll
        for (int mi = 0; mi < 2; mi++)
#pragma unroll
            for (int ni = 0; ni < 4; ni++) {
                const int cl = wn * 64 + ni * 16 + l15;
                const int el = wm * 32 + mi * 16 + (kq << 2);
                const f32x4 v = acc[mi * 4 + ni];
#pragma unroll
                for (int r = 0; r < 4; r++) Cs[cl * 67 + el + r] = v[r];
            }
    }
    // finw mini-GEMM (col = 640 + l15, valid l15<8)
    {
        f32x4 a2[2] = {zz, zz};
        bf16x8 bz;
#pragma unroll
        for (int jj = 0; jj < 8; jj++) bz[jj] = 0;
#pragma unroll
        for (int ks = 0; ks < 5; ks++) {
            const int kc = ks * 4 + kq;
            const bf16x8 b = (l15 < 8)
                ? *(const bf16x8*)(BtF + (kc * 672 + 640 + l15) * 8) : bz;
            a2[0] = __builtin_amdgcn_mfma_f32_16x16x32_bf16(aF0[ks], b, a2[0], 0, 0, 0);
            a2[1] = __builtin_amdgcn_mfma_f32_16x16x32_bf16(aF1[ks], b, a2[1], 0, 0, 0);
        }
        if (wn == 0) {
#pragma unroll
            for (int mi = 0; mi < 2; mi++) {
                const int el = wm * 32 + mi * 16 + (kq << 2);
#pragma unroll
                for (int r = 0; r < 4; r++) Cwf[l15 * 67 + el + r] = a2[mi][r];
            }
        }
    }
    __syncthreads();
    if (t < 192) {
        const int te = t % 64;
        const int dd = t / 64;
        const int eg = eb + te;
        const int d = 1 + dd;
        float f1v[8], nfv[8];
#pragma unroll
        for (int q = 0; q < 4; q++) {
            unpack2(feat1T[(size_t)(d * 4 + q) * EE + eg], f1v[2 * q], f1v[2 * q + 1]);
            unpack2(newfT[(size_t)(d * 4 + q) * EE + eg], nfv[2 * q], nfv[2 * q + 1]);
        }
        float od = 0.f;
#pragma unroll
        for (int u = 0; u < 8; u++) {
            float s = 0.f;
#pragma unroll
            for (int v8 = 0; v8 < 8; v8++)
                s += Cs[(u * 8 + v8) * 67 + te] * f1v[v8] + Cs[(64 + u * 8 + v8) * 67 + te] * nfv[v8];
            od = fmaf(Cwf[u * 67 + te], s, od);
        }
        outp[(size_t)eg * 3 + dd] = od * (HALF_INV_SQM * INV_SQM);
    }
}

// ---------------------------------------------------------------------------
extern "C" void kernel_launch(void* const* d_in, const int* in_sizes, int n_in,
                              void* d_out, int out_size, void* d_ws, size_t ws_size,
                              hipStream_t stream)
{
    const float* ea   = (const float*)d_in[0];
    const float* eemb = (const float*)d_in[1];
    const float* nat  = (const float*)d_in[2];
    const float* elen = (const float*)d_in[3];
    const float* w0   = (const float*)d_in[4];
    const float* w1   = (const float*)d_in[5];
    const float* w2   = (const float*)d_in[6];
    const float* wm0  = (const float*)d_in[7];
    const float* wm1  = (const float*)d_in[8];
    const float* envl = (const float*)d_in[9];
    const float* latw = (const float*)d_in[10];
    const float* l2fn = (const float*)d_in[11];
    const float* l2fo = (const float*)d_in[12];
    const float* finw = (const float*)d_in[13];
    const int*   eidx = (const int*)d_in[14];

    char* ws = (char*)d_ws;
    short*    latf8s = (short*)(ws + 0);               // [E/32][20][32][8] bf16
    short*    h08    = (short*)(ws + 51200000);        // [E/32][16][32][8] bf16 (dead after kAm)
    unsigned* newfT  = (unsigned*)(ws + 92160000);     // [36][EE] u32; aliased wcur0
    unsigned* feat1T = (unsigned*)(ws + 115200000);    // [36][EE] u32
    float*    winiF  = (float*)(ws + 138240000);       // [24][EE] f32
    bf16*     eaT    = (bf16*)(ws + 153600000);        // [9][EE]
    float*    cutb   = (float*)(ws + 156480000);       // [E]
    float*    env0   = (float*)(ws + 157120000);       // [N*72]
    float*    env1   = (float*)(ws + 160000000);       // [N*72]
    int*      deg    = (int*)(ws + 162880000);         // [N] (reused as wAtF)
    int*      cur    = (int*)(ws + 162920000);
    int*      off    = (int*)(ws + 162960000);
    int*      elist  = (int*)(ws + 163000192);
    short*    wAtF   = (short*)(ws + 162880000);       // [16][304][8] bf16
    short*    BtF    = (short*)(ws + 163640192);       // [20][672][8] bf16

    float* wcur0 = (float*)newfT;
    float* wcur1 = (float*)h08;    // h08 dead after kAm; NOT aliasing newfT (kFX race)

    hipMemsetAsync(deg, 0, 80000, stream);

    kCnt <<<625, 256, 0, stream>>>(eidx, deg);
    kScan<<<1, 256, 0, stream>>>(deg, off);
    kFill<<<625, 256, 0, stream>>>(eidx, cur, off, elist);
    kPrepA<<<152, 256, 0, stream>>>(w1, w2, wm0, wAtF);  // overwrites deg/cur (dead)
    kPrepB<<<dim3(3, 160), 256, 0, stream>>>(l2fo, l2fn, latw,
                                             l2fo + 29184, l2fn + 29184, finw, wm1, BtF);

    kA0<<<625, 256, 0, stream>>>(ea, eemb, nat, elen, w0, eidx, h08, latf8s, eaT, cutb);
    kAm<<<2500, 256, 0, stream>>>(h08, wAtF, cutb, latf8s, winiF, wcur0);
    kEnvG<<<352, 256, 0, stream>>>(wcur0, ea, off, elist, envl + 0, env0);
    kC1<<<625, 256, 0, stream>>>(winiF, eaT, env0, eidx, newfT, latf8s);

    kFX<<<2500, 256, 0, stream>>>(latf8s, BtF, winiF, eaT, newfT, cutb, feat1T, wcur1);
    kEnvG<<<352, 256, 0, stream>>>(wcur1, ea, off, elist, envl + 192, env1);
    kE1<<<625, 256, 0, stream>>>(feat1T, env1, eidx, newfT, latf8s);
    kF2<<<2500, 256, 0, stream>>>(latf8s, BtF, feat1T, newfT, (float*)d_out);
}

// Round 14
// 290.480 us; speedup vs baseline: 1.1807x; 1.1807x over previous
//
#include <hip/hip_runtime.h>
#include <hip/hip_bf16.h>

#define EE 160000
#define NNODES 10000

using bf16 = __hip_bfloat16;
using bf16x8 = __attribute__((ext_vector_type(8))) short;
using short4v = __attribute__((ext_vector_type(4))) short;
using f32x4  = __attribute__((ext_vector_type(4))) float;

__device__ __forceinline__ float silu_f(float x) { return x / (1.0f + __expf(-x)); }
__device__ __forceinline__ float b2f(bf16 v) { return __bfloat162float(v); }
__device__ __forceinline__ bf16 f2b(float v) { return __float2bfloat16(v); }

__device__ __forceinline__ unsigned bfbits(float v) {
    union { float f; unsigned u; } a; a.f = v;
    return (a.u + 0x7fffu + ((a.u >> 16) & 1u)) >> 16;
}
__device__ __forceinline__ unsigned pack2(float a, float b) {
    return bfbits(a) | (bfbits(b) << 16);
}
__device__ __forceinline__ void unpack2(unsigned u, float& a, float& b) {
    union { unsigned x; float f; } lo, hi;
    lo.x = u << 16; hi.x = u & 0xffff0000u;
    a = lo.f; b = hi.f;
}
__device__ __forceinline__ float bs2f(short s) {
    union { unsigned u; float f; } x; x.u = ((unsigned)(unsigned short)s) << 16;
    return x.f;
}

// 1/(16*sqrt(8)), 0.5/sqrt(8), 1/sqrt(8)
#define INV_AVGN_SQM 0.02209708691207961f
#define HALF_INV_SQM 0.17677669529663687f
#define INV_SQM      0.35355339059327373f

// ---------------------------------------------------------------------------
// CSR build
// ---------------------------------------------------------------------------
__global__ void kCnt(const int* __restrict__ eidx, int* __restrict__ deg)
{
    const int e = blockIdx.x * 256 + threadIdx.x;
    atomicAdd(&deg[eidx[e]], 1);
}

__global__ void kScan(const int* __restrict__ deg, int* __restrict__ off)
{
    __shared__ int part[256];
    const int t = threadIdx.x;
    int loc[40];
    int s = 0;
#pragma unroll
    for (int i = 0; i < 40; i++) {
        const int idx = t * 40 + i;
        const int v = (idx < NNODES) ? deg[idx] : 0;
        loc[i] = s;
        s += v;
    }
    part[t] = s;
    __syncthreads();
    for (int d = 1; d < 256; d <<= 1) {
        const int v = (t >= d) ? part[t - d] : 0;
        __syncthreads();
        part[t] += v;
        __syncthreads();
    }
    const int base = (t == 0) ? 0 : part[t - 1];
#pragma unroll
    for (int i = 0; i < 40; i++) {
        const int idx = t * 40 + i;
        if (idx < NNODES) off[idx] = base + loc[i];
    }
    if (t == 255) off[NNODES] = part[255];
}

__global__ void kFill(const int* __restrict__ eidx, int* __restrict__ cur,
                      const int* __restrict__ off, int* __restrict__ elist)
{
    const int e = blockIdx.x * 256 + threadIdx.x;
    const int c = eidx[e];
    const int pos = atomicAdd(&cur[c], 1);
    elist[off[c] + pos] = e;
}

// ---------------------------------------------------------------------------
// kPrepA: w1/w2/wm0 -> wAtF fragment-major bf16 [kc=k/8][304 cols][8]
// ---------------------------------------------------------------------------
__global__ void kPrepA(const float* __restrict__ w1, const float* __restrict__ w2,
                       const float* __restrict__ wm0, short* __restrict__ wAtF)
{
    const int t = blockIdx.x * 256 + threadIdx.x;
    if (t >= 38912) return;
    const int k = t & 127, c = t >> 7;
    float v;
    if (c < 128)      v = w1[k * 128 + c];
    else if (c < 256) v = w2[k * 128 + (c - 128)];
    else              v = wm0[k * 48 + (c - 256)];
    wAtF[((k >> 3) * 304 + c) * 8 + (k & 7)] = (short)bfbits(v);
}

// ---------------------------------------------------------------------------
// kPrepB: -> BtF fragment-major bf16 [kc][672][8]
//  cols 0..383: layer-0 per-irrep ; 384..511: latw ; 512..575: l2fo1(+64)
//  576..639: l2fn1(+64) ; 640..647: finw ; 648..671: wm1 (K=128)
// ---------------------------------------------------------------------------
__global__ void kPrepB(const float* __restrict__ l2fo, const float* __restrict__ l2fn,
                       const float* __restrict__ latw, const float* __restrict__ l2fo1,
                       const float* __restrict__ l2fn1, const float* __restrict__ finw,
                       const float* __restrict__ wm1, short* __restrict__ BtF)
{
    const int k = blockIdx.y;
    const int col = blockIdx.x * 256 + threadIdx.x;
    if (col >= 672) return;
    float v = 0.f;
    if (col < 648) {
        if (k < 152) {
            if (col < 384) {
                const int ir = col >> 7, half = (col >> 6) & 1, q = col & 63;
                const float* src = half ? l2fn : l2fo;
                v = src[k * 192 + ir * 64 + q];
            } else if (col < 512)  v = latw[k * 128 + (col - 384)];
            else if (col < 576)    v = l2fo1[k * 192 + 64 + (col - 512)];
            else if (col < 640)    v = l2fn1[k * 192 + 64 + (col - 576)];
            else                   v = finw[k * 8 + (col - 640)];
        }
    } else {
        if (k < 128) v = wm1[k * 24 + (col - 648)];
    }
    BtF[((k >> 3) * 672 + col) * 8 + (k & 7)] = (short)bfbits(v);
}

// ---------------------------------------------------------------------------
// kEnvG: gather env + fused env-linear (per node,d)
// ---------------------------------------------------------------------------
__global__ void kEnvG(const float* __restrict__ wcur, const float* __restrict__ ea,
                      const int* __restrict__ off, const int* __restrict__ elist,
                      const float* __restrict__ wl, float* __restrict__ envc)
{
    const int t = blockIdx.x * 256 + threadIdx.x;
    if (t >= NNODES * 9) return;
    const int n = t / 9;
    const int d = t - n * 9;
    const int irr = (d == 0) ? 0 : ((d < 4) ? 1 : 2);
    float v[8];
#pragma unroll
    for (int q = 0; q < 8; q++) v[q] = 0.0f;
    const int b = off[n], en = off[n + 1];
    for (int j = b; j < en; j++) {
        const int e = elist[j];
        const float ad = ea[e * 9 + d];
        const float* wr = wcur + (size_t)e * 24 + irr;
#pragma unroll
        for (int q = 0; q < 8; q++) v[q] = fmaf(wr[q * 3], ad, v[q]);
    }
#pragma unroll
    for (int u = 0; u < 8; u++) {
        float s = 0.0f;
#pragma unroll
        for (int q = 0; q < 8; q++) s = fmaf(wl[irr * 64 + u * 8 + q], v[q], s);
        envc[n * 72 + u * 9 + d] = s * INV_AVGN_SQM;
    }
}

// ---------------------------------------------------------------------------
// kA0: inputs gather + cutoff + stage0 (16->128) -> h08; eaT; pad chunk
// ---------------------------------------------------------------------------
__global__ __launch_bounds__(256) void kA0(
    const float* __restrict__ ea, const float* __restrict__ eemb,
    const float* __restrict__ nat, const float* __restrict__ elen,
    const float* __restrict__ w0, const int* __restrict__ eidx,
    short* __restrict__ h08, short* __restrict__ latf8s,
    bf16* __restrict__ eaT, float* __restrict__ cutb)
{
    __shared__ float w0s[16 * 128];
    const int t = threadIdx.x;
    const int e = blockIdx.x * 256 + t;
#pragma unroll
    for (int p = 0; p < 8; p++) { const int idx = p * 256 + t; w0s[idx] = w0[idx]; }
    __syncthreads();

    const int ctr = eidx[e];
    const int ngb = eidx[EE + e];
    float tin[16];
#pragma unroll
    for (int k = 0; k < 4; k++) tin[k] = nat[ctr * 4 + k];
#pragma unroll
    for (int k = 0; k < 4; k++) tin[4 + k] = nat[ngb * 4 + k];
#pragma unroll
    for (int k = 0; k < 8; k++) tin[8 + k] = eemb[e * 8 + k];

    const float x = elen[e];
    const float x2 = x * x, x4 = x2 * x2, x6 = x4 * x2, x7 = x6 * x, x8 = x7 * x;
    float cutv = 1.0f - 28.0f * x6 + 48.0f * x7 - 21.0f * x8;
    cutv = (x < 1.0f) ? cutv : 0.0f;
    cutb[e] = cutv;

    const size_t tb = (size_t)(e >> 5);
    const int el = e & 31;
#pragma unroll
    for (int jc = 0; jc < 4; jc++) {
        float a[32];
#pragma unroll
        for (int j = 0; j < 32; j++) a[j] = 0.0f;
#pragma unroll
        for (int k = 0; k < 16; k++) {
            const float v = tin[k];
#pragma unroll
            for (int j = 0; j < 32; j++) a[j] = fmaf(v, w0s[k * 128 + jc * 32 + j], a[j]);
        }
#pragma unroll
        for (int cc = 0; cc < 4; cc++) {
            bf16x8 hv;
#pragma unroll
            for (int jj = 0; jj < 8; jj++) hv[jj] = (short)bfbits(silu_f(a[cc * 8 + jj]));
            *(bf16x8*)(h08 + tb * 4096 + (jc * 4 + cc) * 256 + el * 8) = hv;
        }
    }
    bf16x8 z;
#pragma unroll
    for (int jj = 0; jj < 8; jj++) z[jj] = 0;
    *(bf16x8*)(latf8s + tb * 5120 + 19 * 256 + el * 8) = z;

#pragma unroll
    for (int d = 0; d < 9; d++) eaT[(size_t)d * EE + e] = f2b(ea[e * 9 + d]);
}

// ---------------------------------------------------------------------------
// kAm: MFMA chain. B direct from global wAtF; LDS = A2/A3 (32KB) -> 4 blk/CU.
// ---------------------------------------------------------------------------
__global__ __launch_bounds__(256, 4) void kAm(
    const short* __restrict__ h08, const short* __restrict__ wAtF,
    const float* __restrict__ cutb, short* __restrict__ latf8s,
    float* __restrict__ winiF, float* __restrict__ wcur0)
{
    __shared__ alignas(16) char a2raw[16384];                // A2 / Cs (16 KB)
    __shared__ short A3[8192];                               // 16 KB
    short* A2 = (short*)a2raw;
    float* Cs = (float*)a2raw;

    const int t = threadIdx.x;
    const int eb = blockIdx.x * 64;
    const int lane = t & 63, wid = t >> 6;
    const int wm = wid >> 1, wn = wid & 1;
    const int l15 = lane & 15, kq = lane >> 4;
    const f32x4 zz = {0.f, 0.f, 0.f, 0.f};

    float cutR[2][4];
#pragma unroll
    for (int mi = 0; mi < 2; mi++)
#pragma unroll
        for (int r = 0; r < 4; r++)
            cutR[mi][r] = cutb[eb + wm * 32 + mi * 16 + kq * 4 + r];

    // GEMM1: h1 = silu(h0 @ w1) -> A2   (B cols 0..127)
    {
        f32x4 acc[8];
#pragma unroll
        for (int q = 0; q < 8; q++) acc[q] = zz;
        const size_t ab = (size_t)((eb >> 5) + wm) * 4096 + l15 * 8;
#pragma unroll
        for (int ks = 0; ks < 4; ks++) {
            const int kc = ks * 4 + kq;
            const bf16x8 a0 = *(const bf16x8*)(h08 + ab + kc * 256);
            const bf16x8 a1 = *(const bf16x8*)(h08 + ab + kc * 256 + 128);
            const short* bp = wAtF + (kc * 304 + wn * 64 + l15) * 8;
#pragma unroll
            for (int ni = 0; ni < 4; ni++) {
                const bf16x8 b = *(const bf16x8*)(bp + ni * 16 * 8);
                acc[ni]     = __builtin_amdgcn_mfma_f32_16x16x32_bf16(a0, b, acc[ni], 0, 0, 0);
                acc[4 + ni] = __builtin_amdgcn_mfma_f32_16x16x32_bf16(a1, b, acc[4 + ni], 0, 0, 0);
            }
        }
#pragma unroll
        for (int mi = 0; mi < 2; mi++)
#pragma unroll
            for (int ni = 0; ni < 4; ni++) {
                const int kcol = wn * 64 + ni * 16 + l15;
                const int eb2 = wm * 32 + mi * 16 + (kq << 2);
#pragma unroll
                for (int r = 0; r < 4; r++)
                    A2[(kcol >> 3) * 512 + (eb2 + r) * 8 + (kcol & 7)] =
                        (short)bfbits(silu_f(acc[mi * 4 + ni][r]));
            }
    }
    __syncthreads();

    // GEMM2: latents = (h1 @ w2) * cut -> A3   (B cols 128..255)
    {
        f32x4 acc[8];
#pragma unroll
        for (int q = 0; q < 8; q++) acc[q] = zz;
#pragma unroll
        for (int ks = 0; ks < 4; ks++) {
            const int kc = ks * 4 + kq;
            const bf16x8 a0 = *(const bf16x8*)(A2 + kc * 512 + (wm * 32 + l15) * 8);
            const bf16x8 a1 = *(const bf16x8*)(A2 + kc * 512 + (wm * 32 + 16 + l15) * 8);
            const short* bp = wAtF + (kc * 304 + 128 + wn * 64 + l15) * 8;
#pragma unroll
            for (int ni = 0; ni < 4; ni++) {
                const bf16x8 b = *(const bf16x8*)(bp + ni * 16 * 8);
                acc[ni]     = __builtin_amdgcn_mfma_f32_16x16x32_bf16(a0, b, acc[ni], 0, 0, 0);
                acc[4 + ni] = __builtin_amdgcn_mfma_f32_16x16x32_bf16(a1, b, acc[4 + ni], 0, 0, 0);
            }
        }
#pragma unroll
        for (int mi = 0; mi < 2; mi++)
#pragma unroll
            for (int ni = 0; ni < 4; ni++) {
                const int kcol = wn * 64 + ni * 16 + l15;
                const int eb2 = wm * 32 + mi * 16 + (kq << 2);
#pragma unroll
                for (int r = 0; r < 4; r++)
                    A3[(kcol >> 3) * 512 + (eb2 + r) * 8 + (kcol & 7)] =
                        (short)bfbits(acc[mi * 4 + ni][r] * cutR[mi][r]);
            }
    }
    __syncthreads();
    // copy A3 -> latf8 (coalesced)
#pragma unroll
    for (int p = 0; p < 4; p++) {
        const int i = p * 256 + t;
        const int e = i & 63, kc = i >> 6;
        const bf16x8 v = *(const bf16x8*)(A3 + kc * 512 + e * 8);
        const int eg = eb + e;
        *(bf16x8*)(latf8s + (size_t)(eg >> 5) * 5120 + kc * 256 + (eg & 31) * 8) = v;
    }

    // GEMM3: ewv = latents @ wm0 (wn==0) -> Cs [48][65]   (B cols 256..303)
    if (wn == 0) {
        f32x4 acc[6];
#pragma unroll
        for (int q = 0; q < 6; q++) acc[q] = zz;
#pragma unroll
        for (int ks = 0; ks < 4; ks++) {
            const int kc = ks * 4 + kq;
            const bf16x8 a0 = *(const bf16x8*)(A3 + kc * 512 + (wm * 32 + l15) * 8);
            const bf16x8 a1 = *(const bf16x8*)(A3 + kc * 512 + (wm * 32 + 16 + l15) * 8);
            const short* bp = wAtF + (kc * 304 + 256 + l15) * 8;
#pragma unroll
            for (int ni = 0; ni < 3; ni++) {
                const bf16x8 b = *(const bf16x8*)(bp + ni * 16 * 8);
                acc[ni]     = __builtin_amdgcn_mfma_f32_16x16x32_bf16(a0, b, acc[ni], 0, 0, 0);
                acc[3 + ni] = __builtin_amdgcn_mfma_f32_16x16x32_bf16(a1, b, acc[3 + ni], 0, 0, 0);
            }
        }
#pragma unroll
        for (int mi = 0; mi < 2; mi++)
#pragma unroll
            for (int ni = 0; ni < 3; ni++) {
                const int c = ni * 16 + l15;
                const int eb2 = wm * 32 + mi * 16 + (kq << 2);
#pragma unroll
                for (int r = 0; r < 4; r++)
                    Cs[c * 65 + eb2 + r] = acc[mi * 3 + ni][r];
            }
    }
    __syncthreads();
    for (int i = t; i < 1536; i += 256) {
        const int c = i >> 6, e = i & 63;
        winiF[(size_t)c * EE + eb + e] = Cs[c * 65 + e];
    }
    for (int i = t; i < 1536; i += 256) {
        const int e2 = i / 24, c2 = i - e2 * 24;
        wcur0[(size_t)(eb + e2) * 24 + c2] = Cs[(24 + c2) * 65 + e2];
    }
}

// ---------------------------------------------------------------------------
// kC1: layer-0 interact + invariants
// ---------------------------------------------------------------------------
__global__ __launch_bounds__(256, 1) void kC1(
    const float* __restrict__ winiF, const bf16* __restrict__ eaT,
    const float* __restrict__ envc, const int* __restrict__ eidx,
    unsigned* __restrict__ newfT, short* __restrict__ latf8s)
{
    const int e = blockIdx.x * 256 + threadIdx.x;
    const int ctr = eidx[e];
    float eav[9];
#pragma unroll
    for (int d = 0; d < 9; d++) eav[d] = b2f(eaT[(size_t)d * EE + e]);
    const float* ec = envc + ctr * 72;
    float inv[24];
#pragma unroll
    for (int uh = 0; uh < 4; uh++) {
        const int u0 = 2 * uh;
        float wi0[3], wi1[3];
#pragma unroll
        for (int i = 0; i < 3; i++) {
            wi0[i] = winiF[(size_t)(u0 * 3 + i) * EE + e];
            wi1[i] = winiF[(size_t)((u0 + 1) * 3 + i) * EE + e];
        }
        float nf0[9], nf1[9];
        const float ec00 = ec[u0 * 9 + 0];
        const float ec10 = ec[(u0 + 1) * 9 + 0];
        const float f00 = wi0[0] * eav[0];
        const float f10 = wi1[0] * eav[0];
#pragma unroll
        for (int d = 0; d < 9; d++) {
            const int irr = (d == 0) ? 0 : ((d < 4) ? 1 : 2);
            const float fa = wi0[irr] * eav[d];
            const float fb = wi1[irr] * eav[d];
            nf0[d] = fa * ec00 + ec[u0 * 9 + d] * f00;
            nf1[d] = fb * ec10 + ec[(u0 + 1) * 9 + d] * f10;
        }
#pragma unroll
        for (int d = 0; d < 9; d++) newfT[(size_t)(d * 4 + uh) * EE + e] = pack2(nf0[d], nf1[d]);
        inv[uh * 6 + 0] = sqrtf(nf0[0] * nf0[0] + 1e-8f);
        inv[uh * 6 + 1] = sqrtf(nf0[1]*nf0[1] + nf0[2]*nf0[2] + nf0[3]*nf0[3] + 1e-8f);
        inv[uh * 6 + 2] = sqrtf(nf0[4]*nf0[4] + nf0[5]*nf0[5] + nf0[6]*nf0[6] + nf0[7]*nf0[7] + nf0[8]*nf0[8] + 1e-8f);
        inv[uh * 6 + 3] = sqrtf(nf1[0] * nf1[0] + 1e-8f);
        inv[uh * 6 + 4] = sqrtf(nf1[1]*nf1[1] + nf1[2]*nf1[2] + nf1[3]*nf1[3] + 1e-8f);
        inv[uh * 6 + 5] = sqrtf(nf1[4]*nf1[4] + nf1[5]*nf1[5] + nf1[6]*nf1[6] + nf1[7]*nf1[7] + nf1[8]*nf1[8] + 1e-8f);
    }
    const size_t tb = (size_t)(e >> 5);
    const int el = e & 31;
#pragma unroll
    for (int j = 0; j < 3; j++) {
        bf16x8 iv;
#pragma unroll
        for (int jj = 0; jj < 8; jj++) iv[jj] = (short)bfbits(inv[j * 8 + jj]);
        *(bf16x8*)(latf8s + tb * 5120 + (16 + j) * 256 + el * 8) = iv;
    }
}

// ---------------------------------------------------------------------------
// kF0: layer-0 pe_linear, one irrep per blockIdx.y (grid 2500 x 3).
// Single GEMM + single sync + epilogue per block. 4 blk/CU.
// ---------------------------------------------------------------------------
__global__ __launch_bounds__(256, 4) void kF0(
    const short* __restrict__ A8, const short* __restrict__ BtF,
    const float* __restrict__ winiF, const bf16* __restrict__ eaT,
    const unsigned* __restrict__ newfT, unsigned* __restrict__ feat1T)
{
    __shared__ float Cs[128 * 67];
    const int t = threadIdx.x;
    const int eb = blockIdx.x * 64;
    const int ir = blockIdx.y;
    const int lane = t & 63, wid = t >> 6;
    const int wm = wid >> 1, wn = wid & 1;
    const int l15 = lane & 15, kq = lane >> 4;
    const f32x4 zz = {0.f, 0.f, 0.f, 0.f};
    const size_t ab = (size_t)((eb >> 5) + wm) * 5120 + l15 * 8;
    const int te = t & 63, uh = t >> 6;
    const int eg = eb + te;

    f32x4 acc[8];
#pragma unroll
    for (int q = 0; q < 8; q++) acc[q] = zz;
#pragma unroll
    for (int ks = 0; ks < 5; ks++) {
        const int kc = ks * 4 + kq;
        const bf16x8 a0 = *(const bf16x8*)(A8 + ab + kc * 256);
        const bf16x8 a1 = *(const bf16x8*)(A8 + ab + kc * 256 + 128);
        const short* bp = BtF + (kc * 672 + ir * 128 + wn * 64 + l15) * 8;
#pragma unroll
        for (int ni = 0; ni < 4; ni++) {
            const bf16x8 b = *(const bf16x8*)(bp + ni * 16 * 8);
            acc[ni]     = __builtin_amdgcn_mfma_f32_16x16x32_bf16(a0, b, acc[ni], 0, 0, 0);
            acc[4 + ni] = __builtin_amdgcn_mfma_f32_16x16x32_bf16(a1, b, acc[4 + ni], 0, 0, 0);
        }
    }
#pragma unroll
    for (int mi = 0; mi < 2; mi++)
#pragma unroll
        for (int ni = 0; ni < 4; ni++) {
            const int cl = wn * 64 + ni * 16 + l15;
            const int el = wm * 32 + mi * 16 + (kq << 2);
            const f32x4 v = acc[mi * 4 + ni];
#pragma unroll
            for (int r = 0; r < 4; r++) Cs[cl * 67 + el + r] = v[r];
        }
    __syncthreads();
    const int d0 = (ir == 0) ? 0 : ((ir == 1) ? 1 : 4);
    const int nd = (ir == 0) ? 1 : ((ir == 1) ? 3 : 5);
    float wv[8];
#pragma unroll
    for (int v8 = 0; v8 < 8; v8++) wv[v8] = winiF[(size_t)(v8 * 3 + ir) * EE + eg];
    for (int dd = 0; dd < nd; dd++) {
        const int d = d0 + dd;
        const float ead = b2f(eaT[(size_t)d * EE + eg]);
        float nfv[8];
#pragma unroll
        for (int q = 0; q < 4; q++)
            unpack2(newfT[(size_t)(d * 4 + q) * EE + eg], nfv[2 * q], nfv[2 * q + 1]);
        float s0 = 0.f, s1 = 0.f;
#pragma unroll
        for (int v8 = 0; v8 < 8; v8++) {
            const float fe = wv[v8] * ead;
            s0 += Cs[(uh * 16 + v8) * 67 + te] * fe + Cs[(64 + uh * 16 + v8) * 67 + te] * nfv[v8];
            s1 += Cs[(uh * 16 + 8 + v8) * 67 + te] * fe + Cs[(64 + uh * 16 + 8 + v8) * 67 + te] * nfv[v8];
        }
        feat1T[(size_t)(d * 4 + uh) * EE + eg] = pack2(s0 * HALF_INV_SQM, s1 * HALF_INV_SQM);
    }
}

// ---------------------------------------------------------------------------
// kF3: fused latw GEMM + latent resnet + env-MLP1 (MFMA mini-GEMM).
// B direct from BtF; LDS = Cc + l1s = 33.4KB -> 4 blk/CU.
// ---------------------------------------------------------------------------
__global__ __launch_bounds__(256, 4) void kF3(
    short* __restrict__ A8, const short* __restrict__ BtF,
    const float* __restrict__ cutb, float* __restrict__ wcur1)
{
    __shared__ alignas(16) short Cc[128 * 68];  // bf16 lat_new [col][e]; reused as Cw (f32)
    __shared__ short l1s[16 * 512];             // l1 A-fragment tile [kc][e][8]
    float* Cw = (float*)Cc;
    const int t = threadIdx.x;
    const int eb = blockIdx.x * 64;
    const int lane = t & 63, wid = t >> 6;
    const int wm = wid >> 1, wn = wid & 1;
    const int l15 = lane & 15, kq = lane >> 4;
    const f32x4 zz = {0.f, 0.f, 0.f, 0.f};

    {
        f32x4 acc[8];
#pragma unroll
        for (int q = 0; q < 8; q++) acc[q] = zz;
        const size_t ab = (size_t)((eb >> 5) + wm) * 5120 + l15 * 8;
#pragma unroll
        for (int ks = 0; ks < 5; ks++) {
            const int kc = ks * 4 + kq;
            const bf16x8 a0 = *(const bf16x8*)(A8 + ab + kc * 256);
            const bf16x8 a1 = *(const bf16x8*)(A8 + ab + kc * 256 + 128);
            const short* bp = BtF + (kc * 672 + 384 + wn * 64 + l15) * 8;
#pragma unroll
            for (int ni = 0; ni < 4; ni++) {
                const bf16x8 b = *(const bf16x8*)(bp + ni * 16 * 8);
                acc[ni]     = __builtin_amdgcn_mfma_f32_16x16x32_bf16(a0, b, acc[ni], 0, 0, 0);
                acc[4 + ni] = __builtin_amdgcn_mfma_f32_16x16x32_bf16(a1, b, acc[4 + ni], 0, 0, 0);
            }
        }
#pragma unroll
        for (int mi = 0; mi < 2; mi++)
#pragma unroll
            for (int ni = 0; ni < 4; ni++) {
                const int cl = wn * 64 + ni * 16 + l15;
                const int el = wm * 32 + mi * 16 + (kq << 2);
                const f32x4 v = acc[mi * 4 + ni];
                short4v pv;
#pragma unroll
                for (int r = 0; r < 4; r++) pv[r] = (short)bfbits(v[r]);
                *(short4v*)(Cc + cl * 68 + el) = pv;
            }
    }
    __syncthreads();
    // epilogue: l1 = 0.5*old + 0.5*silu(lat_new)*cut -> A8 (in place) + l1s
    {
        const int te = t & 63, q = t >> 6;
        const int eg = eb + te;
        const size_t tb = (size_t)(eg >> 5);
        const int el2 = eg & 31;
        const float cutv = cutb[eg];
#pragma unroll
        for (int c = 0; c < 4; c++) {
            const int kc = q * 4 + c;
            short* ap = A8 + tb * 5120 + kc * 256 + el2 * 8;
            const bf16x8 ov = *(const bf16x8*)ap;
            bf16x8 nv;
#pragma unroll
            for (int jj = 0; jj < 8; jj++) {
                const int j = kc * 8 + jj;
                const float g = bs2f(Cc[j * 68 + te]);
                const float o = bs2f(ov[jj]);
                nv[jj] = (short)bfbits(0.5f * o + 0.5f * silu_f(g) * cutv);
            }
            *(bf16x8*)ap = nv;
            *(bf16x8*)(l1s + kc * 512 + te * 8) = nv;
        }
    }
    __syncthreads();   // l1s ready; Cc reads done before Cw overwrite
    // mini-GEMM: wcur1 = l1 @ wm1 (wn==0 waves; B cols 648..671, c<24 valid)
    if (wn == 0) {
        f32x4 acc[4] = {zz, zz, zz, zz};
#pragma unroll
        for (int ks = 0; ks < 4; ks++) {
            const int kc = ks * 4 + kq;
            const bf16x8 a0 = *(const bf16x8*)(l1s + kc * 512 + (wm * 32 + l15) * 8);
            const bf16x8 a1 = *(const bf16x8*)(l1s + kc * 512 + (wm * 32 + 16 + l15) * 8);
#pragma unroll
            for (int ni = 0; ni < 2; ni++) {
                const int c = ni * 16 + l15;
                bf16x8 b;
                if (c < 24) b = *(const bf16x8*)(BtF + (kc * 672 + 648 + c) * 8);
                else {
#pragma unroll
                    for (int jj = 0; jj < 8; jj++) b[jj] = 0;
                }
                acc[ni]     = __builtin_amdgcn_mfma_f32_16x16x32_bf16(a0, b, acc[ni], 0, 0, 0);
                acc[2 + ni] = __builtin_amdgcn_mfma_f32_16x16x32_bf16(a1, b, acc[2 + ni], 0, 0, 0);
            }
        }
#pragma unroll
        for (int mi = 0; mi < 2; mi++)
#pragma unroll
            for (int ni = 0; ni < 2; ni++) {
                const int c = ni * 16 + l15;
                if (c < 24) {
                    const int el = wm * 32 + mi * 16 + (kq << 2);
#pragma unroll
                    for (int r = 0; r < 4; r++) Cw[c * 65 + el + r] = acc[mi * 2 + ni][r];
                }
            }
    }
    __syncthreads();
    for (int i = t; i < 1536; i += 256) {
        const int e2 = i / 24, c2 = i - e2 * 24;
        wcur1[(size_t)(eb + e2) * 24 + c2] = Cw[c2 * 65 + e2];
    }
}

// ---------------------------------------------------------------------------
// kE1: layer-1 interact + invariants
// ---------------------------------------------------------------------------
__global__ __launch_bounds__(256, 1) void kE1(
    const unsigned* __restrict__ feat1T, const float* __restrict__ envc,
    const int* __restrict__ eidx, unsigned* __restrict__ newfT,
    short* __restrict__ latf8s)
{
    const int e = blockIdx.x * 256 + threadIdx.x;
    const int ctr = eidx[e];
    const float* ec = envc + ctr * 72;
    float inv[24];
#pragma unroll
    for (int uh = 0; uh < 4; uh++) {
        const int u0 = 2 * uh;
        float f0[9], f1[9];
#pragma unroll
        for (int d = 0; d < 9; d++) unpack2(feat1T[(size_t)(d * 4 + uh) * EE + e], f0[d], f1[d]);
        const float ec00 = ec[u0 * 9 + 0];
        const float ec10 = ec[(u0 + 1) * 9 + 0];
        float nf0[9], nf1[9];
#pragma unroll
        for (int d = 0; d < 9; d++) {
            nf0[d] = f0[d] * ec00 + ec[u0 * 9 + d] * f0[0];
            nf1[d] = f1[d] * ec10 + ec[(u0 + 1) * 9 + d] * f1[0];
        }
#pragma unroll
        for (int d = 0; d < 9; d++) newfT[(size_t)(d * 4 + uh) * EE + e] = pack2(nf0[d], nf1[d]);
        inv[uh * 6 + 0] = sqrtf(nf0[0] * nf0[0] + 1e-8f);
        inv[uh * 6 + 1] = sqrtf(nf0[1]*nf0[1] + nf0[2]*nf0[2] + nf0[3]*nf0[3] + 1e-8f);
        inv[uh * 6 + 2] = sqrtf(nf0[4]*nf0[4] + nf0[5]*nf0[5] + nf0[6]*nf0[6] + nf0[7]*nf0[7] + nf0[8]*nf0[8] + 1e-8f);
        inv[uh * 6 + 3] = sqrtf(nf1[0] * nf1[0] + 1e-8f);
        inv[uh * 6 + 4] = sqrtf(nf1[1]*nf1[1] + nf1[2]*nf1[2] + nf1[3]*nf1[3] + 1e-8f);
        inv[uh * 6 + 5] = sqrtf(nf1[4]*nf1[4] + nf1[5]*nf1[5] + nf1[6]*nf1[6] + nf1[7]*nf1[7] + nf1[8]*nf1[8] + 1e-8f);
    }
    const size_t tb = (size_t)(e >> 5);
    const int el = e & 31;
#pragma unroll
    for (int j = 0; j < 3; j++) {
        bf16x8 iv;
#pragma unroll
        for (int jj = 0; jj < 8; jj++) iv[jj] = (short)bfbits(inv[j * 8 + jj]);
        *(bf16x8*)(latf8s + tb * 5120 + (16 + j) * 256 + el * 8) = iv;
    }
}

// ---------------------------------------------------------------------------
// kF2: fused final GEMM (accO1|accN1 + finw) + epilogue -> d_out.
// B direct from BtF; LDS 38.6KB -> 4 blk/CU.
// ---------------------------------------------------------------------------
__global__ __launch_bounds__(256, 4) void kF2(
    const short* __restrict__ A8, const short* __restrict__ BtF,
    const unsigned* __restrict__ feat1T, const unsigned* __restrict__ newfT,
    float* __restrict__ outp)
{
    __shared__ float Cs[128 * 67];
    __shared__ float Cwf[16 * 67];
    const int t = threadIdx.x;
    const int eb = blockIdx.x * 64;
    const int lane = t & 63, wid = t >> 6;
    const int wm = wid >> 1, wn = wid & 1;
    const int l15 = lane & 15, kq = lane >> 4;
    const f32x4 zz = {0.f, 0.f, 0.f, 0.f};
    const size_t ab = (size_t)((eb >> 5) + wm) * 5120 + l15 * 8;

    {
        f32x4 acc[8];
#pragma unroll
        for (int q = 0; q < 8; q++) acc[q] = zz;
#pragma unroll
        for (int ks = 0; ks < 5; ks++) {
            const int kc = ks * 4 + kq;
            const bf16x8 a0 = *(const bf16x8*)(A8 + ab + kc * 256);
            const bf16x8 a1 = *(const bf16x8*)(A8 + ab + kc * 256 + 128);
            const short* bp = BtF + (kc * 672 + 512 + wn * 64 + l15) * 8;
#pragma unroll
            for (int ni = 0; ni < 4; ni++) {
                const bf16x8 b = *(const bf16x8*)(bp + ni * 16 * 8);
                acc[ni]     = __builtin_amdgcn_mfma_f32_16x16x32_bf16(a0, b, acc[ni], 0, 0, 0);
                acc[4 + ni] = __builtin_amdgcn_mfma_f32_16x16x32_bf16(a1, b, acc[4 + ni], 0, 0, 0);
            }
        }
#pragma unroll
        for (int mi = 0; mi < 2; mi++)
#pragma unroll
            for (int ni = 0; ni < 4; ni++) {
                const int cl = wn * 64 + ni * 16 + l15;
                const int el = wm * 32 + mi * 16 + (kq << 2);
                const f32x4 v = acc[mi * 4 + ni];
#pragma unroll
                for (int r = 0; r < 4; r++) Cs[cl * 67 + el + r] = v[r];
            }
    }
    // finw mini-GEMM (col = 640 + l15, valid l15<8)
    {
        f32x4 a2[2] = {zz, zz};
        bf16x8 bz;
#pragma unroll
        for (int jj = 0; jj < 8; jj++) bz[jj] = 0;
#pragma unroll
        for (int ks = 0; ks < 5; ks++) {
            const int kc = ks * 4 + kq;
            const bf16x8 a0 = *(const bf16x8*)(A8 + ab + kc * 256);
            const bf16x8 a1 = *(const bf16x8*)(A8 + ab + kc * 256 + 128);
            const bf16x8 b = (l15 < 8)
                ? *(const bf16x8*)(BtF + (kc * 672 + 640 + l15) * 8) : bz;
            a2[0] = __builtin_amdgcn_mfma_f32_16x16x32_bf16(a0, b, a2[0], 0, 0, 0);
            a2[1] = __builtin_amdgcn_mfma_f32_16x16x32_bf16(a1, b, a2[1], 0, 0, 0);
        }
        if (wn == 0) {
#pragma unroll
            for (int mi = 0; mi < 2; mi++) {
                const int el = wm * 32 + mi * 16 + (kq << 2);
#pragma unroll
                for (int r = 0; r < 4; r++) Cwf[l15 * 67 + el + r] = a2[mi][r];
            }
        }
    }
    __syncthreads();
    if (t < 192) {
        const int te = t % 64;
        const int dd = t / 64;
        const int eg = eb + te;
        const int d = 1 + dd;
        float f1v[8], nfv[8];
#pragma unroll
        for (int q = 0; q < 4; q++) {
            unpack2(feat1T[(size_t)(d * 4 + q) * EE + eg], f1v[2 * q], f1v[2 * q + 1]);
            unpack2(newfT[(size_t)(d * 4 + q) * EE + eg], nfv[2 * q], nfv[2 * q + 1]);
        }
        float od = 0.f;
#pragma unroll
        for (int u = 0; u < 8; u++) {
            float s = 0.f;
#pragma unroll
            for (int v8 = 0; v8 < 8; v8++)
                s += Cs[(u * 8 + v8) * 67 + te] * f1v[v8] + Cs[(64 + u * 8 + v8) * 67 + te] * nfv[v8];
            od = fmaf(Cwf[u * 67 + te], s, od);
        }
        outp[(size_t)eg * 3 + dd] = od * (HALF_INV_SQM * INV_SQM);
    }
}

// ---------------------------------------------------------------------------
extern "C" void kernel_launch(void* const* d_in, const int* in_sizes, int n_in,
                              void* d_out, int out_size, void* d_ws, size_t ws_size,
                              hipStream_t stream)
{
    const float* ea   = (const float*)d_in[0];
    const float* eemb = (const float*)d_in[1];
    const float* nat  = (const float*)d_in[2];
    const float* elen = (const float*)d_in[3];
    const float* w0   = (const float*)d_in[4];
    const float* w1   = (const float*)d_in[5];
    const float* w2   = (const float*)d_in[6];
    const float* wm0  = (const float*)d_in[7];
    const float* wm1  = (const float*)d_in[8];
    const float* envl = (const float*)d_in[9];
    const float* latw = (const float*)d_in[10];
    const float* l2fn = (const float*)d_in[11];
    const float* l2fo = (const float*)d_in[12];
    const float* finw = (const float*)d_in[13];
    const int*   eidx = (const int*)d_in[14];

    char* ws = (char*)d_ws;
    short*    latf8s = (short*)(ws + 0);               // [E/32][20][32][8] bf16
    short*    h08    = (short*)(ws + 51200000);        // [E/32][16][32][8] bf16
    unsigned* newfT  = (unsigned*)(ws + 92160000);     // [36][EE] u32; aliased wcur0/1
    unsigned* feat1T = (unsigned*)(ws + 115200000);    // [36][EE] u32
    float*    winiF  = (float*)(ws + 138240000);       // [24][EE] f32
    bf16*     eaT    = (bf16*)(ws + 153600000);        // [9][EE]
    float*    cutb   = (float*)(ws + 156480000);       // [E]
    float*    env0   = (float*)(ws + 157120000);       // [N*72]
    float*    env1   = (float*)(ws + 160000000);       // [N*72]
    int*      deg    = (int*)(ws + 162880000);         // [N] (reused as wAtF)
    int*      cur    = (int*)(ws + 162920000);
    int*      off    = (int*)(ws + 162960000);
    int*      elist  = (int*)(ws + 163000192);
    short*    wAtF   = (short*)(ws + 162880000);       // [16][304][8] bf16
    short*    BtF    = (short*)(ws + 163640192);       // [20][672][8] bf16

    float* wcur0 = (float*)newfT;
    float* wcur1 = (float*)newfT;

    hipMemsetAsync(deg, 0, 80000, stream);

    kCnt <<<625, 256, 0, stream>>>(eidx, deg);
    kScan<<<1, 256, 0, stream>>>(deg, off);
    kFill<<<625, 256, 0, stream>>>(eidx, cur, off, elist);
    kPrepA<<<152, 256, 0, stream>>>(w1, w2, wm0, wAtF);  // overwrites deg/cur (dead)
    kPrepB<<<dim3(3, 160), 256, 0, stream>>>(l2fo, l2fn, latw,
                                             l2fo + 29184, l2fn + 29184, finw, wm1, BtF);

    kA0<<<625, 256, 0, stream>>>(ea, eemb, nat, elen, w0, eidx, h08, latf8s, eaT, cutb);
    kAm<<<2500, 256, 0, stream>>>(h08, wAtF, cutb, latf8s, winiF, wcur0);
    kEnvG<<<352, 256, 0, stream>>>(wcur0, ea, off, elist, envl + 0, env0);
    kC1<<<625, 256, 0, stream>>>(winiF, eaT, env0, eidx, newfT, latf8s);

    kF0<<<dim3(2500, 3), 256, 0, stream>>>(latf8s, BtF, winiF, eaT, newfT, feat1T);
    kF3<<<2500, 256, 0, stream>>>(latf8s, BtF, cutb, wcur1);
    kEnvG<<<352, 256, 0, stream>>>(wcur1, ea, off, elist, envl + 192, env1);
    kE1<<<625, 256, 0, stream>>>(feat1T, env1, eidx, newfT, latf8s);
    kF2<<<2500, 256, 0, stream>>>(latf8s, BtF, feat1T, newfT, (float*)d_out);
}